// Round 15
// baseline (68.969 us; speedup 1.0000x reference)
//
#include <hip/hip_runtime.h>
#include <cstddef>

#define NUM_BLOCKS 8
#define BLK 512
#define D_IN 2048
#define NROWS 8192
#define NBUCKETS (NUM_BLOCKS * BLK) /* 4096 */
#define CAP 32
#define THREADS 512
#define SENT 4096
#define TILES 4                     /* tiles per WG */
#define TROWS 4                     /* rows per tile */
#define NWG (NROWS / (TILES * TROWS)) /* 512 = 2 per CU */

typedef float    v4f __attribute__((ext_vector_type(4)));
typedef unsigned v4u __attribute__((ext_vector_type(4)));

// ---------------- index build (unchanged, proven) ----------------
__global__ __launch_bounds__(256) void cs_build_index(
    const int* __restrict__ i_hash, const float* __restrict__ s_hash,
    int* __restrict__ nchunks, int* __restrict__ entries,
    unsigned short* __restrict__ entries16)
{
    const int gid  = blockIdx.x * blockDim.x + threadIdx.x;
    const int wave = gid >> 6;
    const int lane = threadIdx.x & 63;
    if (wave >= NBUCKETS) return;
    const int b = wave >> 9;
    const int k = wave & (BLK - 1);
    const int*   ih = i_hash + b * D_IN;
    const float* sr = s_hash + b * D_IN;
    int* erow = entries + wave * CAP;
    unsigned short* e16 = entries16 + wave * 8;
    int cnt = 0;
    for (int d0 = 0; d0 < D_IN; d0 += 64) {
        const int d = d0 + lane;
        const bool m = (ih[d] == k);
        const unsigned long long mask = __ballot(m);
        if (m) {
            const int pos = cnt + __popcll(mask & ((1ull << lane) - 1ull));
            const int ent = (d << 1) | ((sr[d] < 0.0f) ? 1 : 0);
            if (pos < CAP) erow[pos] = ent;
            if (pos < 8)   e16[pos]  = (unsigned short)ent;
        }
        cnt += (int)__popcll(mask);
    }
    if (cnt > CAP) cnt = CAP;
    int nch = (cnt + 3) >> 2;
    if (nch == 0) nch = 1;
    if (lane >= cnt) {
        if (lane < 8)       e16[lane]  = (unsigned short)SENT;
        if (lane < nch * 4) erow[lane] = SENT;
    }
    if (lane == 0) nchunks[wave] = nch;
}

// RNE float->bf16 (upper 16 bits).
static __device__ __forceinline__ unsigned bfr(float f) {
    const unsigned u = __float_as_uint(f);
    return (u + 0x7fffu + ((u >> 16) & 1u)) >> 16;
}

// Pipelined gather: 512 WGs (2/CU), each runs TILES=4 tiles of 4 rows.
// Per iter: STAGE(t) -> lgkm-barrier -> store carried g1(t-1) -> compute
// g0(t)+store -> compute g1(t) into carry regs -> barrier. Stores always
// issue just before a compute phase and drain under it (R13: phases were
// summed; this overlaps store-drain with compute). Carry = 16 regs (not a
// staged tile -- avoids R6 spills). Stores issue AFTER stage loads so the
// pack's vmcnt wait doesn't serialize behind them (R9 inverted). Raw
// s_barrier + "memory"-clobber lgkmcnt(0) keeps NT stores in flight
// across barriers. launch_bounds(512,2) relaxes VGPR cap (no spill);
// ~110 VGPR -> 2 WGs/CU resident.
__global__ __launch_bounds__(THREADS, 2) void cs_gather(
    const float* __restrict__ x, const int* __restrict__ nchunks,
    const int* __restrict__ entries, const v4u* __restrict__ entries16,
    float* __restrict__ out)
{
    __shared__ uint2 xs2[D_IN + 1];   // 16.4 KB; [d] = rows 0..3 bf16-packed
    const int tid      = threadIdx.x;
    const int row_base = blockIdx.x * (TILES * TROWS);

    // Descriptors once (same buckets for all tiles).
    v4u e8[8];
    int nch8[8];
#pragma unroll
    for (int g = 0; g < 2; ++g)
#pragma unroll
        for (int q = 0; q < 4; ++q) {
            const int j = 4 * (tid + 512 * g) + q;
            e8[g * 4 + q]  = entries16[j];
            nch8[g * 4 + q] = nchunks[j];
        }
    if (tid == 0) xs2[D_IN] = make_uint2(0u, 0u);  // sentinel row (stays 0)

    const float scale = 0.35355339059327373f; // 1/sqrt(8)
#define ASF __uint_as_float

#define LGKMBAR() do {                                                    \
        asm volatile("s_waitcnt lgkmcnt(0)" ::: "memory");                \
        __builtin_amdgcn_s_barrier();                                     \
    } while (0)

#define STAGE(t) do {                                                     \
        const size_t bs = (size_t)(row_base + (t) * TROWS) * D_IN;        \
        _Pragma("unroll")                                                 \
        for (int i = 0; i < 4; ++i) {                                     \
            const int d = tid + i * THREADS;                              \
            float f0 = x[bs + d];                                         \
            float f1 = x[bs + D_IN + d];                                  \
            float f2 = x[bs + 2 * D_IN + d];                              \
            float f3 = x[bs + 3 * D_IN + d];                              \
            uint2 w;                                                      \
            w.x = bfr(f0) | (bfr(f1) << 16);                              \
            w.y = bfr(f2) | (bfr(f3) << 16);                              \
            xs2[d] = w;                                                   \
        }                                                                 \
    } while (0)

    // One ds_read_b64 + sign-xor covers 4 rows. A = float[4].
#define PE4(e, A)                                                         \
    do {                                                                  \
        const unsigned ue = (unsigned)(e);                                \
        const unsigned sm = (ue & 1u) ? 0x80008000u : 0u;                 \
        const uint2 w = xs2[ue >> 1];                                     \
        const unsigned w0 = w.x ^ sm, w1 = w.y ^ sm;                      \
        A[0] += ASF(w0 << 16); A[1] += ASF(w0 & 0xffff0000u);             \
        A[2] += ASF(w1 << 16); A[3] += ASF(w1 & 0xffff0000u);             \
    } while (0)

    // Compute one bucket-group (4 buckets) into ACC[q][rr].
#define COMPG(gb, ACC) do {                                               \
        _Pragma("unroll")                                                 \
        for (int q = 0; q < 4; ++q)                                       \
            _Pragma("unroll")                                             \
            for (int rr = 0; rr < 4; ++rr) ACC[q][rr] = 0.0f;             \
        _Pragma("unroll")                                                 \
        for (int q = 0; q < 4; ++q) {                                     \
            const v4u ew = e8[(gb) * 4 + q];                              \
            PE4(ew.x & 0xffffu, ACC[q]); PE4(ew.x >> 16, ACC[q]);         \
            PE4(ew.y & 0xffffu, ACC[q]); PE4(ew.y >> 16, ACC[q]);         \
            PE4(ew.z & 0xffffu, ACC[q]); PE4(ew.z >> 16, ACC[q]);         \
            PE4(ew.w & 0xffffu, ACC[q]);                                  \
            PE4(ew.w >> 16, ACC[q]);                                      \
            const int n = nch8[(gb) * 4 + q];                             \
            if (n > 2) {                                                  \
                const int j = 4 * (tid + 512 * (gb)) + q;                 \
                const int4* __restrict__ ep =                             \
                    (const int4*)(entries + j * CAP);                     \
                _Pragma("unroll 1")                                       \
                for (int c = 2; c < n; ++c) {                             \
                    const int4 cc = ep[c];                                \
                    PE4(cc.x, ACC[q]); PE4(cc.y, ACC[q]);                 \
                    PE4(cc.z, ACC[q]); PE4(cc.w, ACC[q]);                 \
                }                                                         \
            }                                                             \
        }                                                                 \
    } while (0)

    // Store one group's 4 buckets for tile t: 4 NT float4 (coalesced).
#define STOREG(gb, t, ACC) do {                                           \
        const int c4 = tid + 512 * (gb);                                  \
        _Pragma("unroll")                                                 \
        for (int rr = 0; rr < 4; ++rr) {                                  \
            v4f v = { ACC[0][rr] * scale, ACC[1][rr] * scale,             \
                      ACC[2][rr] * scale, ACC[3][rr] * scale };           \
            __builtin_nontemporal_store(                                  \
                v, (v4f*)(out + (size_t)(row_base + (t) * TROWS + rr) *   \
                          NBUCKETS + 4 * c4));                            \
        }                                                                 \
    } while (0)

    float a0[4][4];   // g0 accumulator (stored within the iteration)
    float c1[4][4];   // g1 accumulator (carried across the barrier)

    // ---- prologue: tile 0 ----
    STAGE(0);
    LGKMBAR();
    COMPG(0, a0); STOREG(0, 0, a0);    // g0 stores drain under g1 compute
    COMPG(1, c1);                       // carried
    LGKMBAR();

    // ---- steady state: tiles 1..TILES-1 ----
#pragma unroll 1
    for (int t = 1; t < TILES; ++t) {
        STAGE(t);                       // loads issue before any new stores
        LGKMBAR();
        STOREG(1, t - 1, c1);           // carry store drains under compute
        COMPG(0, a0); STOREG(0, t, a0);
        COMPG(1, c1);
        LGKMBAR();
    }

    // ---- epilogue ----
    STOREG(1, TILES - 1, c1);

#undef STOREG
#undef COMPG
#undef PE4
#undef STAGE
#undef LGKMBAR
#undef ASF
}

extern "C" void kernel_launch(void* const* d_in, const int* in_sizes, int n_in,
                              void* d_out, int out_size, void* d_ws, size_t ws_size,
                              hipStream_t stream)
{
    const float* x      = (const float*)d_in[0];
    const float* s_hash = (const float*)d_in[1];
    const int*   i_hash = (const int*)d_in[2];
    float* out = (float*)d_out;

    int* nchunks = (int*)d_ws;
    int* entries = nchunks + NBUCKETS;
    unsigned short* entries16 = (unsigned short*)(entries + NBUCKETS * CAP);

    cs_build_index<<<(NBUCKETS * 64) / 256, 256, 0, stream>>>(
        i_hash, s_hash, nchunks, entries, entries16);
    cs_gather<<<NWG, THREADS, 0, stream>>>(
        x, nchunks, entries, (const v4u*)entries16, out);
}

// Round 16
// 55.048 us; speedup vs baseline: 1.2529x; 1.2529x over previous
//
#include <hip/hip_runtime.h>
#include <cstddef>

#define NUM_BLOCKS 8
#define BLK 512
#define D_IN 2048
#define NROWS 8192
#define NBUCKETS (NUM_BLOCKS * BLK) /* 4096 */
#define CAP 32
#define ROWS_PER_WG 8
#define THREADS 512
#define SENT 4096

typedef float    v2f __attribute__((ext_vector_type(2)));
typedef float    v4f __attribute__((ext_vector_type(4)));
typedef unsigned v4u __attribute__((ext_vector_type(4)));

// ---------------- index build (unchanged, proven) ----------------
__global__ __launch_bounds__(256) void cs_build_index(
    const int* __restrict__ i_hash, const float* __restrict__ s_hash,
    int* __restrict__ nchunks, int* __restrict__ entries,
    unsigned short* __restrict__ entries16)
{
    const int gid  = blockIdx.x * blockDim.x + threadIdx.x;
    const int wave = gid >> 6;
    const int lane = threadIdx.x & 63;
    if (wave >= NBUCKETS) return;
    const int b = wave >> 9;
    const int k = wave & (BLK - 1);
    const int*   ih = i_hash + b * D_IN;
    const float* sr = s_hash + b * D_IN;
    int* erow = entries + wave * CAP;
    unsigned short* e16 = entries16 + wave * 8;
    int cnt = 0;
    for (int d0 = 0; d0 < D_IN; d0 += 64) {
        const int d = d0 + lane;
        const bool m = (ih[d] == k);
        const unsigned long long mask = __ballot(m);
        if (m) {
            const int pos = cnt + __popcll(mask & ((1ull << lane) - 1ull));
            const int ent = (d << 1) | ((sr[d] < 0.0f) ? 1 : 0);
            if (pos < CAP) erow[pos] = ent;
            if (pos < 8)   e16[pos]  = (unsigned short)ent;
        }
        cnt += (int)__popcll(mask);
    }
    if (cnt > CAP) cnt = CAP;
    int nch = (cnt + 3) >> 2;
    if (nch == 0) nch = 1;
    if (lane >= cnt) {
        if (lane < 8)       e16[lane]  = (unsigned short)SENT;
        if (lane < nch * 4) erow[lane] = SENT;
    }
    if (lane == 0) nchunks[wave] = nch;
}

// Gather (R14 = best measured, 55.24 us total): R8 inner structure with
// stores spread into 4 wave-staggered clusters. Thread t owns 8 buckets
// as 4 groups of 2: group g -> buckets 2*(t+512g)+{0,1}; wave w processes
// groups starting at (w&3). Descriptors loaded into wave-rotated SLOTS so
// register indexing stays static (no scratch). bf16 transposed tile
// (xs4[d] = 8 rows in 16B; one ds_read_b128 per entry serves 8 rows);
// sentinel row 2048 is zeros; fmaf(+-1) PE; NT dwordx2 stores.
__global__ __launch_bounds__(THREADS, 4) void cs_gather(
    const float* __restrict__ x, const int* __restrict__ nchunks,
    const int* __restrict__ entries, const v4u* __restrict__ entries16,
    float* __restrict__ out)
{
    __shared__ v4u xs4[D_IN + 1];   // 32784 B; row d = 8 bf16 (rows 0..7)
    const int tid  = threadIdx.x;
    const int wv   = tid >> 6;      // wave id 0..7
    const int row0 = blockIdx.x * ROWS_PER_WG;

    // Descriptors into wave-rotated slots (slot s holds group (s+wv)&3).
    v4u e8[8];
    int nch8[8];
#pragma unroll
    for (int s = 0; s < 4; ++s) {
        const int g = (s + wv) & 3;
#pragma unroll
        for (int q = 0; q < 2; ++q) {
            const int j = 2 * (tid + 512 * g) + q;
            e8[s * 2 + q]  = entries16[j];
            nch8[s * 2 + q] = nchunks[j];
        }
    }

    if (tid == 0) xs4[D_IN] = (v4u){0u, 0u, 0u, 0u};  // sentinel row

    // Stage transposed bf16: 8 coalesced dword loads -> RNE pack ->
    // 1 ds_write_b128 per owned d.
    const size_t b0 = (size_t)row0 * D_IN;
#pragma unroll
    for (int i = 0; i < 4; ++i) {
        const int d = tid + i * THREADS;
        unsigned r[8];
#pragma unroll
        for (int rr = 0; rr < 8; ++rr) {
            const unsigned u = __float_as_uint(x[b0 + (size_t)rr * D_IN + d]);
            r[rr] = (u + 0x7fffu + ((u >> 16) & 1u)) >> 16;  // RNE bf16
        }
        v4u w;
        w.x = r[0] | (r[1] << 16); w.y = r[2] | (r[3] << 16);
        w.z = r[4] | (r[5] << 16); w.w = r[6] | (r[7] << 16);
        xs4[d] = w;
    }
    __syncthreads();

    const float scale = 0.35355339059327373f; // 1/sqrt(8)
#define ASF __uint_as_float

    // One b128 read; sign via fmaf(+-1); sentinel -> zeros row (exact noop).
#define PE(e, A)                                                          \
    do {                                                                  \
        const unsigned ue = (unsigned)(e);                                \
        const float sg = (ue & 1u) ? -1.0f : 1.0f;                        \
        const v4u w = xs4[ue >> 1];                                       \
        A[0] = fmaf(sg, ASF(w.x << 16),         A[0]);                    \
        A[1] = fmaf(sg, ASF(w.x & 0xffff0000u), A[1]);                    \
        A[2] = fmaf(sg, ASF(w.y << 16),         A[2]);                    \
        A[3] = fmaf(sg, ASF(w.y & 0xffff0000u), A[3]);                    \
        A[4] = fmaf(sg, ASF(w.z << 16),         A[4]);                    \
        A[5] = fmaf(sg, ASF(w.z & 0xffff0000u), A[5]);                    \
        A[6] = fmaf(sg, ASF(w.w << 16),         A[6]);                    \
        A[7] = fmaf(sg, ASF(w.w & 0xffff0000u), A[7]);                    \
    } while (0)

#pragma unroll
    for (int s = 0; s < 4; ++s) {           // static slot loop
        const int g    = (s + wv) & 3;      // runtime group (address only)
        const int col2 = tid + 512 * g;
        float acc[2][8];
#pragma unroll
        for (int q = 0; q < 2; ++q)
#pragma unroll
            for (int rr = 0; rr < 8; ++rr) acc[q][rr] = 0.0f;

#pragma unroll
        for (int q = 0; q < 2; ++q) {
            const v4u ew = e8[s * 2 + q];
            PE(ew.x & 0xffffu, acc[q]); PE(ew.x >> 16, acc[q]);
            PE(ew.y & 0xffffu, acc[q]); PE(ew.y >> 16, acc[q]);
            PE(ew.z & 0xffffu, acc[q]); PE(ew.z >> 16, acc[q]);
            PE(ew.w & 0xffffu, acc[q]);
            PE(ew.w >> 16, acc[q]);
            const int n = nch8[s * 2 + q];
            if (n > 2) {                    // rare (~2% of buckets)
                const int j = 2 * col2 + q;
                const int4* __restrict__ ep = (const int4*)(entries + j * CAP);
#pragma unroll 1
                for (int c = 2; c < n; ++c) {
                    const int4 cc = ep[c];
                    PE(cc.x, acc[q]); PE(cc.y, acc[q]);
                    PE(cc.z, acc[q]); PE(cc.w, acc[q]);
                }
            }
        }
        // Store this group's 2 buckets immediately: 8 NT dwordx2 stores.
#pragma unroll
        for (int rr = 0; rr < 8; ++rr) {
            v2f v = { acc[0][rr] * scale, acc[1][rr] * scale };
            __builtin_nontemporal_store(
                v, (v2f*)(out + (size_t)(row0 + rr) * NBUCKETS + 2 * col2));
        }
    }
#undef PE
#undef ASF
}

extern "C" void kernel_launch(void* const* d_in, const int* in_sizes, int n_in,
                              void* d_out, int out_size, void* d_ws, size_t ws_size,
                              hipStream_t stream)
{
    const float* x      = (const float*)d_in[0];
    const float* s_hash = (const float*)d_in[1];
    const int*   i_hash = (const int*)d_in[2];
    float* out = (float*)d_out;

    int* nchunks = (int*)d_ws;
    int* entries = nchunks + NBUCKETS;
    unsigned short* entries16 = (unsigned short*)(entries + NBUCKETS * CAP);

    cs_build_index<<<(NBUCKETS * 64) / 256, 256, 0, stream>>>(
        i_hash, s_hash, nchunks, entries, entries16);
    cs_gather<<<NROWS / ROWS_PER_WG, THREADS, 0, stream>>>(
        x, nchunks, entries, (const v4u*)entries16, out);
}